// Round 1
// baseline (205.413 us; speedup 1.0000x reference)
//
#include <hip/hip_runtime.h>
#include <stdint.h>

// Problem: B=2, T=2048, C=1024, H=16, HD=64. M = B*T = 4096, 3C = 3072.
// Geo bias folded into Q:  q~[d] = q[d]*SCALE + hs*(q[:8]·dir)*dir[d] (d<8)

typedef float f32x4 __attribute__((ext_vector_type(4)));
typedef unsigned short u16x8 __attribute__((ext_vector_type(8)));
typedef unsigned short u16x4 __attribute__((ext_vector_type(4)));
typedef __bf16 bf16x8 __attribute__((ext_vector_type(8)));

static __device__ __forceinline__ unsigned short f2bf(float f) {
  unsigned u = __float_as_uint(f);
  u += 0x7FFFu + ((u >> 16) & 1u);
  return (unsigned short)(u >> 16);
}
static __device__ __forceinline__ float bf2f(unsigned short s) {
  return __uint_as_float(((unsigned)s) << 16);
}
static __device__ __forceinline__ f32x4 mfma16(u16x8 a, u16x8 b, f32x4 c) {
  return __builtin_amdgcn_mfma_f32_16x16x32_bf16(
      __builtin_bit_cast(bf16x8, a), __builtin_bit_cast(bf16x8, b), c, 0, 0, 0);
}

#define GLD16(gp, lp) __builtin_amdgcn_global_load_lds( \
    (const __attribute__((address_space(1))) unsigned int*)(gp), \
    (__attribute__((address_space(3))) unsigned int*)(lp), 16, 0, 0)

// ---------------- cast x (fp32 -> bf16) ----------------
__global__ __launch_bounds__(256) void k_cast(const float* __restrict__ in,
                                              unsigned short* __restrict__ out, int n4) {
  int i = blockIdx.x * 256 + threadIdx.x;
  if (i >= n4) return;
  f32x4 v = *(const f32x4*)(in + (size_t)i * 4);
  u16x4 o;
#pragma unroll
  for (int j = 0; j < 4; ++j) o[j] = f2bf(v[j]);
  *(u16x4*)(out + (size_t)i * 4) = o;
}

// ---------------- transpose + cast: out[c][r] = bf16(in[r][c]) ----------------
__global__ __launch_bounds__(256) void k_transpose(const float* __restrict__ in,
                                                   unsigned short* __restrict__ out,
                                                   int R, int Cc) {
  __shared__ float t[64][65];
  int tr = blockIdx.y * 64, tc = blockIdx.x * 64;
  int tx = threadIdx.x & 15, ty = threadIdx.x >> 4;
#pragma unroll
  for (int i = 0; i < 4; ++i) {
    int rr = ty + i * 16;
    f32x4 v = *(const f32x4*)(in + (size_t)(tr + rr) * Cc + tc + tx * 4);
#pragma unroll
    for (int j = 0; j < 4; ++j) t[rr][tx * 4 + j] = v[j];
  }
  __syncthreads();
#pragma unroll
  for (int i = 0; i < 4; ++i) {
    int cc = ty + i * 16;
    int rr = tx * 4;
    u16x4 o;
#pragma unroll
    for (int j = 0; j < 4; ++j) o[j] = f2bf(t[rr + j][cc]);
    *(u16x4*)(out + (size_t)(tc + cc) * R + tr + rr) = o;
  }
}

// ---------------- GEMM: C[m][n] = sum_k A[m][k] * Bt[n][k]  (K=1024, 128x128 tile, BK=32)
// MODE 0: epilogue scatters Q,K as [BH][T][64] bf16 and V as [BH][64][T] bf16 (transposed)
// MODE 1: epilogue stores fp32 row-major [M][1024]
template <int MODE>
__global__ __launch_bounds__(256) void k_gemm(const unsigned short* __restrict__ A,
                                              const unsigned short* __restrict__ Bt,
                                              unsigned short* __restrict__ qo,
                                              unsigned short* __restrict__ ko,
                                              unsigned short* __restrict__ vTo,
                                              float* __restrict__ fo) {
  __shared__ unsigned short lA[128 * 32];
  __shared__ unsigned short lB[128 * 32];
  const int tid = threadIdx.x;
  const int lane = tid & 63, wid = tid >> 6;
  const int wr = wid >> 1, wc = wid & 1;
  const int r = lane & 15, g = lane >> 4;
  const int mbase = blockIdx.y * 128;
  const int nbase = blockIdx.x * 128;

  f32x4 acc[4][4] = {};

  for (int kt = 0; kt < 32; ++kt) {
    __syncthreads();
#pragma unroll
    for (int p = 0; p < 2; ++p) {
      int L = p * 4096 + tid * 16;  // byte offset in 8KB tile
      int row = L >> 6;             // 64B per row (32 bf16)
      int blk = (L >> 4) & 3;       // 16B block within row
      GLD16(A + (size_t)(mbase + row) * 1024 + kt * 32 + blk * 8, lA + (L >> 1));
      GLD16(Bt + (size_t)(nbase + row) * 1024 + kt * 32 + blk * 8, lB + (L >> 1));
    }
    __syncthreads();
    u16x8 af[4], bfv[4];
#pragma unroll
    for (int m = 0; m < 4; ++m)
      af[m] = *(const u16x8*)(lA + (wr * 64 + m * 16 + r) * 32 + g * 8);
#pragma unroll
    for (int n = 0; n < 4; ++n)
      bfv[n] = *(const u16x8*)(lB + (wc * 64 + n * 16 + r) * 32 + g * 8);
#pragma unroll
    for (int m = 0; m < 4; ++m)
#pragma unroll
      for (int n = 0; n < 4; ++n) acc[m][n] = mfma16(af[m], bfv[n], acc[m][n]);
  }

#pragma unroll
  for (int m = 0; m < 4; ++m) {
#pragma unroll
    for (int n = 0; n < 4; ++n) {
      int ng = nbase + wc * 64 + n * 16 + r;
      int m0 = mbase + wr * 64 + m * 16 + g * 4;
      if (MODE == 0) {
        int sec = ng >> 10, rem = ng & 1023, hh = rem >> 6, d = rem & 63;
        int b = m0 >> 11, t0 = m0 & 2047;
        size_t bh = (size_t)(b * 16 + hh);
        if (sec == 2) {
          u16x4 o;
#pragma unroll
          for (int e = 0; e < 4; ++e) o[e] = f2bf(acc[m][n][e]);
          *(u16x4*)(vTo + (bh * 64 + d) * 2048 + t0) = o;  // V^T: [bh][d][t]
        } else {
          unsigned short* dst = (sec == 0 ? qo : ko);
#pragma unroll
          for (int e = 0; e < 4; ++e)
            dst[(bh * 2048 + t0 + e) * 64 + d] = f2bf(acc[m][n][e]);
        }
      } else {
#pragma unroll
        for (int e = 0; e < 4; ++e)
          fo[(size_t)(m0 + e) * 1024 + ng] = acc[m][n][e];
      }
    }
  }
}

// ---------------- causal flash attention, head_dim 64, folded E8 bias ----------------
// grid: (qt=32, bh=32); 256 threads = 4 waves x 16 q-rows; KBLK=64
__global__ __launch_bounds__(256) void k_attn(const unsigned short* __restrict__ qb,
                                              const unsigned short* __restrict__ kb,
                                              const unsigned short* __restrict__ vTb,
                                              const float* __restrict__ hsc,
                                              const float* __restrict__ hdir,
                                              unsigned short* __restrict__ o2) {
  __shared__ unsigned short lK[64 * 64];   // [kpos][d], XOR-swizzled rows
  __shared__ unsigned short lV[64 * 64];   // [d][kpos], XOR-swizzled rows
  __shared__ unsigned short lP[4][16 * 64];  // per-wave P bounce, swizzled

  const int tid = threadIdx.x, lane = tid & 63, wid = tid >> 6;
  const int r = lane & 15, g = lane >> 4;
  const int bh = blockIdx.y, h = bh & 15, bi = bh >> 4;
  const int qt = blockIdx.x;
  const int qw = qt * 64 + wid * 16;

  const float hs = hsc[h];
  float dir8[8];
#pragma unroll
  for (int j = 0; j < 8; ++j) dir8[j] = hdir[h * 8 + j];

  // Build folded Q~ fragments (A-operand: lane holds row q=r, d-chunk g)
  const unsigned short* qrow = qb + ((size_t)bh * 2048 + qw + r) * 64;
  float proj = 0.f;
  {
    u16x8 qv = *(const u16x8*)qrow;
#pragma unroll
    for (int j = 0; j < 8; ++j) proj += bf2f(qv[j]) * dir8[j];
  }
  u16x8 qf[2];
#pragma unroll
  for (int s = 0; s < 2; ++s) {
    int d0 = s * 32 + g * 8;
    u16x8 raw = *(const u16x8*)(qrow + d0);
    u16x8 ov;
#pragma unroll
    for (int j = 0; j < 8; ++j) {
      float v = bf2f(raw[j]) * 0.125f;
      if (s == 0) {
        if (g == 0) v += hs * proj * dir8[j];  // d = j < 8 only when s==0 && g==0
      }
      ov[j] = f2bf(v);
    }
    qf[s] = ov;
  }

  f32x4 accO[4] = {};
  float mrow[4] = {-1e30f, -1e30f, -1e30f, -1e30f};
  float lrow[4] = {0.f, 0.f, 0.f, 0.f};

  const size_t kbase = (size_t)bh * 2048 * 64;
  const size_t vbase = (size_t)bh * 64 * 2048;

  for (int kt = 0; kt <= qt; ++kt) {
    __syncthreads();
    // Stage K,V tiles (8KB each). Linear LDS dest; source pre-swizzled so reads
    // can XOR-swizzle (byte ^= (row&7)<<4) -> bank-conflict-free ds_read_b128.
#pragma unroll
    for (int p = 0; p < 2; ++p) {
      int L = p * 4096 + tid * 16;
      int row = L >> 7;           // 128B rows (64 bf16)
      int cb = (L >> 4) & 7;
      int cbg = cb ^ (row & 7);
      GLD16(kb + kbase + (size_t)(kt * 64 + row) * 64 + cbg * 8, (unsigned short*)lK + (L >> 1));
      GLD16(vTb + vbase + (size_t)row * 2048 + kt * 64 + cbg * 8, (unsigned short*)lV + (L >> 1));
    }
    __syncthreads();

    // S = Q~ @ K^T   (4 col-tiles of 16 kpos, 2 MFMA each over d=64)
    f32x4 accS[4];
#pragma unroll
    for (int ct = 0; ct < 4; ++ct) {
      f32x4 s4 = {0.f, 0.f, 0.f, 0.f};
#pragma unroll
      for (int s = 0; s < 2; ++s) {
        int krow = ct * 16 + r;
        int byt = krow * 128 + ((s * 64 + g * 16) ^ ((krow & 7) << 4));
        u16x8 kf = *(const u16x8*)((const char*)lK + byt);
        s4 = mfma16(qf[s], kf, s4);
      }
      accS[ct] = s4;
    }

    if (kt == qt) {  // diagonal tile: causal mask
#pragma unroll
      for (int ct = 0; ct < 4; ++ct)
#pragma unroll
        for (int e = 0; e < 4; ++e) {
          int kk = kt * 64 + ct * 16 + r;
          int qq = qw + g * 4 + e;
          if (kk > qq) accS[ct][e] = -1e30f;
        }
    }

    // online softmax; S layout: lane holds S[q=g*4+e][k=ct*16+r]
    float alpha[4];
#pragma unroll
    for (int e = 0; e < 4; ++e) {
      float v = fmaxf(fmaxf(accS[0][e], accS[1][e]), fmaxf(accS[2][e], accS[3][e]));
#pragma unroll
      for (int off = 1; off < 16; off <<= 1) v = fmaxf(v, __shfl_xor(v, off, 64));
      float mn = fmaxf(mrow[e], v);
      alpha[e] = __expf(mrow[e] - mn);
      mrow[e] = mn;
    }
    float rsum[4] = {0.f, 0.f, 0.f, 0.f};
    unsigned short pbv[4][4];
#pragma unroll
    for (int ct = 0; ct < 4; ++ct)
#pragma unroll
      for (int e = 0; e < 4; ++e) {
        float p = __expf(accS[ct][e] - mrow[e]);
        rsum[e] += p;
        pbv[ct][e] = f2bf(p);
      }
#pragma unroll
    for (int e = 0; e < 4; ++e) {
      float v = rsum[e];
#pragma unroll
      for (int off = 1; off < 16; off <<= 1) v += __shfl_xor(v, off, 64);
      lrow[e] = lrow[e] * alpha[e] + v;
    }
#pragma unroll
    for (int dt = 0; dt < 4; ++dt)
#pragma unroll
      for (int e = 0; e < 4; ++e) accO[dt][e] *= alpha[e];

    // P bounce through per-wave LDS (C-layout -> A-fragment layout), swizzled
    unsigned short* pw = &lP[wid][0];
#pragma unroll
    for (int ct = 0; ct < 4; ++ct)
#pragma unroll
      for (int e = 0; e < 4; ++e) {
        int qq = g * 4 + e;
        int kk = ct * 16 + r;
        *(unsigned short*)((char*)pw + qq * 128 + ((kk * 2) ^ ((qq & 7) << 4))) = pbv[ct][e];
      }
    asm volatile("s_waitcnt lgkmcnt(0)" ::: "memory");
    __builtin_amdgcn_sched_barrier(0);

    // O += P @ V  (A: lane holds P[q=r][k-chunk g]; B from V^T LDS)
#pragma unroll
    for (int s = 0; s < 2; ++s) {
      u16x8 pa = *(const u16x8*)((const char*)pw + r * 128 + ((s * 64 + g * 16) ^ ((r & 7) << 4)));
#pragma unroll
      for (int dt = 0; dt < 4; ++dt) {
        int dd = dt * 16 + r;
        u16x8 vf = *(const u16x8*)((const char*)lV + dd * 128 + ((s * 64 + g * 16) ^ ((dd & 7) << 4)));
        accO[dt] = mfma16(pa, vf, accO[dt]);
      }
    }
  }

  // epilogue: O/l -> bf16 [B,T,C] (attention output, input to final GEMM)
#pragma unroll
  for (int e = 0; e < 4; ++e) {
    float inv = 1.f / lrow[e];
    int qq = qw + g * 4 + e;
#pragma unroll
    for (int dt = 0; dt < 4; ++dt)
      o2[((size_t)(bi * 2048 + qq)) * 1024 + h * 64 + dt * 16 + r] = f2bf(accO[dt][e] * inv);
  }
}

extern "C" void kernel_launch(void* const* d_in, const int* in_sizes, int n_in,
                              void* d_out, int out_size, void* d_ws, size_t ws_size,
                              hipStream_t stream) {
  const float* x    = (const float*)d_in[0];
  const float* wqkv = (const float*)d_in[1];
  const float* wout = (const float*)d_in[2];
  const float* hsc  = (const float*)d_in[3];
  const float* hdir = (const float*)d_in[4];
  float* outp = (float*)d_out;

  char* ws = (char*)d_ws;
  unsigned short* xb    = (unsigned short*)(ws + 0);         //  8 MB  [4096][1024]
  unsigned short* wqkvT = (unsigned short*)(ws + 8388608);   //  6 MB  [3072][1024]
  unsigned short* woutT = (unsigned short*)(ws + 14680064);  //  2 MB  [1024][1024]
  unsigned short* qb    = (unsigned short*)(ws + 16777216);  //  8 MB  [32][2048][64]
  unsigned short* kb    = (unsigned short*)(ws + 25165824);  //  8 MB  [32][2048][64]
  unsigned short* vT    = (unsigned short*)(ws + 33554432);  //  8 MB  [32][64][2048]
  unsigned short* x2b   = (unsigned short*)(ws + 41943040);  //  8 MB  [4096][1024]
  if (ws_size < 50331648u) return;

  k_cast<<<4096, 256, 0, stream>>>(x, xb, 1048576);
  k_transpose<<<dim3(48, 16), 256, 0, stream>>>(wqkv, wqkvT, 1024, 3072);
  k_transpose<<<dim3(16, 16), 256, 0, stream>>>(wout, woutT, 1024, 1024);
  k_gemm<0><<<dim3(24, 32), 256, 0, stream>>>(xb, wqkvT, qb, kb, vT, nullptr);
  k_attn<<<dim3(32, 32), 256, 0, stream>>>(qb, kb, vT, hsc, hdir, x2b);
  k_gemm<1><<<dim3(8, 32), 256, 0, stream>>>(x2b, woutT, nullptr, nullptr, nullptr, outp);
}

// Round 2
// 199.522 us; speedup vs baseline: 1.0295x; 1.0295x over previous
//
#include <hip/hip_runtime.h>
#include <stdint.h>

// Problem: B=2, T=2048, C=1024, H=16, HD=64. M = B*T = 4096, 3C = 3072.
// Geo bias folded into Q:  q~[d] = q[d]*SCALE + hs*(q[:8]·dir)*dir[d] (d<8)
// log2(e) additionally folded into Q~ so softmax uses exp2 directly.

typedef float f32x4 __attribute__((ext_vector_type(4)));
typedef unsigned short u16x8 __attribute__((ext_vector_type(8)));
typedef unsigned short u16x4 __attribute__((ext_vector_type(4)));
typedef __bf16 bf16x8 __attribute__((ext_vector_type(8)));

static __device__ __forceinline__ unsigned short f2bf(float f) {
  unsigned u = __float_as_uint(f);
  u += 0x7FFFu + ((u >> 16) & 1u);
  return (unsigned short)(u >> 16);
}
static __device__ __forceinline__ float bf2f(unsigned short s) {
  return __uint_as_float(((unsigned)s) << 16);
}
static __device__ __forceinline__ f32x4 mfma16(u16x8 a, u16x8 b, f32x4 c) {
  return __builtin_amdgcn_mfma_f32_16x16x32_bf16(
      __builtin_bit_cast(bf16x8, a), __builtin_bit_cast(bf16x8, b), c, 0, 0, 0);
}

#define GLD16(gp, lp) __builtin_amdgcn_global_load_lds( \
    (const __attribute__((address_space(1))) unsigned int*)(gp), \
    (__attribute__((address_space(3))) unsigned int*)(lp), 16, 0, 0)

// ---------------- cast x (fp32 -> bf16) ----------------
__global__ __launch_bounds__(256) void k_cast(const float* __restrict__ in,
                                              unsigned short* __restrict__ out, int n4) {
  int i = blockIdx.x * 256 + threadIdx.x;
  if (i >= n4) return;
  f32x4 v = *(const f32x4*)(in + (size_t)i * 4);
  u16x4 o;
#pragma unroll
  for (int j = 0; j < 4; ++j) o[j] = f2bf(v[j]);
  *(u16x4*)(out + (size_t)i * 4) = o;
}

// ---------------- transpose + cast: out[c][r] = bf16(in[r][c]) ----------------
__global__ __launch_bounds__(256) void k_transpose(const float* __restrict__ in,
                                                   unsigned short* __restrict__ out,
                                                   int R, int Cc) {
  __shared__ float t[64][65];
  int tr = blockIdx.y * 64, tc = blockIdx.x * 64;
  int tx = threadIdx.x & 15, ty = threadIdx.x >> 4;
#pragma unroll
  for (int i = 0; i < 4; ++i) {
    int rr = ty + i * 16;
    f32x4 v = *(const f32x4*)(in + (size_t)(tr + rr) * Cc + tc + tx * 4);
#pragma unroll
    for (int j = 0; j < 4; ++j) t[rr][tx * 4 + j] = v[j];
  }
  __syncthreads();
#pragma unroll
  for (int i = 0; i < 4; ++i) {
    int cc = ty + i * 16;
    int rr = tx * 4;
    u16x4 o;
#pragma unroll
    for (int j = 0; j < 4; ++j) o[j] = f2bf(t[rr + j][cc]);
    *(u16x4*)(out + (size_t)(tc + cc) * R + tr + rr) = o;
  }
}

// ---------------- GEMM: C[m][n] = sum_k A[m][k] * Bt[n][k]  (K=1024, 128x128 tile, BK=32)
template <int MODE>
__global__ __launch_bounds__(256) void k_gemm(const unsigned short* __restrict__ A,
                                              const unsigned short* __restrict__ Bt,
                                              unsigned short* __restrict__ qo,
                                              unsigned short* __restrict__ ko,
                                              unsigned short* __restrict__ vTo,
                                              float* __restrict__ fo) {
  __shared__ unsigned short lA[128 * 32];
  __shared__ unsigned short lB[128 * 32];
  const int tid = threadIdx.x;
  const int lane = tid & 63, wid = tid >> 6;
  const int wr = wid >> 1, wc = wid & 1;
  const int r = lane & 15, g = lane >> 4;
  const int mbase = blockIdx.y * 128;
  const int nbase = blockIdx.x * 128;

  f32x4 acc[4][4] = {};

  for (int kt = 0; kt < 32; ++kt) {
    __syncthreads();
#pragma unroll
    for (int p = 0; p < 2; ++p) {
      int L = p * 4096 + tid * 16;  // byte offset in 8KB tile
      int row = L >> 6;             // 64B per row (32 bf16)
      int blk = (L >> 4) & 3;       // 16B block within row
      GLD16(A + (size_t)(mbase + row) * 1024 + kt * 32 + blk * 8, lA + (L >> 1));
      GLD16(Bt + (size_t)(nbase + row) * 1024 + kt * 32 + blk * 8, lB + (L >> 1));
    }
    __syncthreads();
    u16x8 af[4], bfv[4];
#pragma unroll
    for (int m = 0; m < 4; ++m)
      af[m] = *(const u16x8*)(lA + (wr * 64 + m * 16 + r) * 32 + g * 8);
#pragma unroll
    for (int n = 0; n < 4; ++n)
      bfv[n] = *(const u16x8*)(lB + (wc * 64 + n * 16 + r) * 32 + g * 8);
#pragma unroll
    for (int m = 0; m < 4; ++m)
#pragma unroll
      for (int n = 0; n < 4; ++n) acc[m][n] = mfma16(af[m], bfv[n], acc[m][n]);
  }

#pragma unroll
  for (int m = 0; m < 4; ++m) {
#pragma unroll
    for (int n = 0; n < 4; ++n) {
      int ng = nbase + wc * 64 + n * 16 + r;
      int m0 = mbase + wr * 64 + m * 16 + g * 4;
      if (MODE == 0) {
        int sec = ng >> 10, rem = ng & 1023, hh = rem >> 6, d = rem & 63;
        int b = m0 >> 11, t0 = m0 & 2047;
        size_t bh = (size_t)(b * 16 + hh);
        if (sec == 2) {
          u16x4 o;
#pragma unroll
          for (int e = 0; e < 4; ++e) o[e] = f2bf(acc[m][n][e]);
          *(u16x4*)(vTo + (bh * 64 + d) * 2048 + t0) = o;  // V^T: [bh][d][t]
        } else {
          unsigned short* dst = (sec == 0 ? qo : ko);
#pragma unroll
          for (int e = 0; e < 4; ++e)
            dst[(bh * 2048 + t0 + e) * 64 + d] = f2bf(acc[m][n][e]);
        }
      } else {
#pragma unroll
        for (int e = 0; e < 4; ++e)
          fo[(size_t)(m0 + e) * 1024 + ng] = acc[m][n][e];
      }
    }
  }
}

// ---------------- causal flash attention, head_dim 64, folded E8 bias ----------------
// grid: 1024 1-D blocks; qt scrambled vs bh so co-resident blocks on a CU mix
// heavy/light diagonals. 256 threads = 4 waves x 16 q-rows; KBLK=64.
// Double-buffered K/V staging, ONE raw s_barrier per K-iteration.
__global__ __launch_bounds__(256) void k_attn(const unsigned short* __restrict__ qb,
                                              const unsigned short* __restrict__ kb,
                                              const unsigned short* __restrict__ vTb,
                                              const float* __restrict__ hsc,
                                              const float* __restrict__ hdir,
                                              unsigned short* __restrict__ o2) {
  __shared__ unsigned short lK[2][64 * 64];   // [buf][kpos][d], XOR-swizzled rows
  __shared__ unsigned short lV[2][64 * 64];   // [buf][d][kpos], XOR-swizzled rows
  __shared__ unsigned short lP[4][16 * 64];   // per-wave P bounce, swizzled

  const int tid = threadIdx.x, lane = tid & 63, wid = tid >> 6;
  const int r = lane & 15, g = lane >> 4;
  const int bid = blockIdx.x;
  const int bh = bid >> 5;
  const int qt = ((bid & 31) + bh) & 31;   // de-align qt across co-resident blocks
  const int h = bh & 15, bi = bh >> 4;
  const int qw = qt * 64 + wid * 16;

  const size_t kbase = (size_t)bh * 2048 * 64;
  const size_t vbase = (size_t)bh * 64 * 2048;

  auto STAGE = [&](int buf, int kt) {
#pragma unroll
    for (int p = 0; p < 2; ++p) {
      int L = p * 4096 + tid * 16;
      int row = L >> 7;           // 128B rows (64 bf16)
      int cb = (L >> 4) & 7;
      int cbg = cb ^ (row & 7);   // pre-swizzled source -> swizzled reads, linear dest
      GLD16(kb + kbase + (size_t)(kt * 64 + row) * 64 + cbg * 8, lK[buf] + (L >> 1));
      GLD16(vTb + vbase + (size_t)row * 2048 + kt * 64 + cbg * 8, lV[buf] + (L >> 1));
    }
  };

  STAGE(0, 0);  // prologue staging overlaps Q-fragment build below

  const float LOG2E = 1.44269504088896f;
  const float hs = hsc[h];
  float dir8[8];
#pragma unroll
  for (int j = 0; j < 8; ++j) dir8[j] = hdir[h * 8 + j];

  // Build folded Q~ fragments (A-operand: lane holds row q=r, d-chunk g)
  const unsigned short* qrow = qb + ((size_t)bh * 2048 + qw + r) * 64;
  float proj = 0.f;
  {
    u16x8 qv = *(const u16x8*)qrow;
#pragma unroll
    for (int j = 0; j < 8; ++j) proj += bf2f(qv[j]) * dir8[j];
  }
  u16x8 qf[2];
#pragma unroll
  for (int s = 0; s < 2; ++s) {
    int d0 = s * 32 + g * 8;
    u16x8 raw = *(const u16x8*)(qrow + d0);
    u16x8 ov;
#pragma unroll
    for (int j = 0; j < 8; ++j) {
      float v = bf2f(raw[j]) * (0.125f * LOG2E);
      if (s == 0) {
        if (g == 0) v += (hs * LOG2E) * proj * dir8[j];  // d = j < 8 only when s==0 && g==0
      }
      ov[j] = f2bf(v);
    }
    qf[s] = ov;
  }

  f32x4 accO[4] = {};
  float mrow[4] = {-1e30f, -1e30f, -1e30f, -1e30f};
  float lrow[4] = {0.f, 0.f, 0.f, 0.f};

  asm volatile("s_waitcnt vmcnt(0)" ::: "memory");
  __builtin_amdgcn_sched_barrier(0);
  __builtin_amdgcn_s_barrier();

  int cur = 0;
  for (int kt = 0; kt <= qt; ++kt) {
    if (kt < qt) STAGE(cur ^ 1, kt + 1);  // prefetch next tile into other buffer

    const char* lKc = (const char*)lK[cur];
    const char* lVc = (const char*)lV[cur];

    // S' = Q~ @ K^T (in log2 domain)
    f32x4 accS[4];
    __builtin_amdgcn_s_setprio(1);
#pragma unroll
    for (int ct = 0; ct < 4; ++ct) {
      f32x4 s4 = {0.f, 0.f, 0.f, 0.f};
#pragma unroll
      for (int s = 0; s < 2; ++s) {
        int krow = ct * 16 + r;
        int byt = krow * 128 + ((s * 64 + g * 16) ^ ((krow & 7) << 4));
        u16x8 kf = *(const u16x8*)(lKc + byt);
        s4 = mfma16(qf[s], kf, s4);
      }
      accS[ct] = s4;
    }
    __builtin_amdgcn_s_setprio(0);

    if (kt == qt) {  // diagonal tile: causal mask
#pragma unroll
      for (int ct = 0; ct < 4; ++ct)
#pragma unroll
        for (int e = 0; e < 4; ++e) {
          int kk = kt * 64 + ct * 16 + r;
          int qq = qw + g * 4 + e;
          if (kk > qq) accS[ct][e] = -1e30f;
        }
    }

    // online softmax (exp2 domain); lane holds S[q=g*4+e][k=ct*16+r]
    float alpha[4];
#pragma unroll
    for (int e = 0; e < 4; ++e) {
      float v = fmaxf(fmaxf(accS[0][e], accS[1][e]), fmaxf(accS[2][e], accS[3][e]));
#pragma unroll
      for (int off = 1; off < 16; off <<= 1) v = fmaxf(v, __shfl_xor(v, off, 64));
      float mn = fmaxf(mrow[e], v);
      alpha[e] = exp2f(mrow[e] - mn);
      mrow[e] = mn;
    }
    float rsum[4] = {0.f, 0.f, 0.f, 0.f};
    unsigned short pbv[4][4];
#pragma unroll
    for (int ct = 0; ct < 4; ++ct)
#pragma unroll
      for (int e = 0; e < 4; ++e) {
        float p = exp2f(accS[ct][e] - mrow[e]);
        rsum[e] += p;
        pbv[ct][e] = f2bf(p);
      }
#pragma unroll
    for (int e = 0; e < 4; ++e) {
      float v = rsum[e];
#pragma unroll
      for (int off = 1; off < 16; off <<= 1) v += __shfl_xor(v, off, 64);
      lrow[e] = lrow[e] * alpha[e] + v;
    }
#pragma unroll
    for (int dt = 0; dt < 4; ++dt)
#pragma unroll
      for (int e = 0; e < 4; ++e) accO[dt][e] *= alpha[e];

    // P bounce through per-wave LDS (C-layout -> A-fragment layout), swizzled
    unsigned short* pw = &lP[wid][0];
#pragma unroll
    for (int ct = 0; ct < 4; ++ct)
#pragma unroll
      for (int e = 0; e < 4; ++e) {
        int qq = g * 4 + e;
        int kk = ct * 16 + r;
        *(unsigned short*)((char*)pw + qq * 128 + ((kk * 2) ^ ((qq & 7) << 4))) = pbv[ct][e];
      }
    asm volatile("s_waitcnt lgkmcnt(0)" ::: "memory");
    __builtin_amdgcn_sched_barrier(0);

    // O += P @ V  (A: lane holds P[q=r][k-chunk g]; B from V^T LDS)
    __builtin_amdgcn_s_setprio(1);
#pragma unroll
    for (int s = 0; s < 2; ++s) {
      u16x8 pa = *(const u16x8*)((const char*)pw + r * 128 + ((s * 64 + g * 16) ^ ((r & 7) << 4)));
#pragma unroll
      for (int dt = 0; dt < 4; ++dt) {
        int dd = dt * 16 + r;
        u16x8 vf = *(const u16x8*)(lVc + dd * 128 + ((s * 64 + g * 16) ^ ((dd & 7) << 4)));
        accO[dt] = mfma16(pa, vf, accO[dt]);
      }
    }
    __builtin_amdgcn_s_setprio(0);

    // single barrier per iteration: own stores landed (vmcnt0), own LDS reads
    // retired (lgkmcnt0), then rendezvous -> next tile ready for ALL waves.
    asm volatile("s_waitcnt vmcnt(0) lgkmcnt(0)" ::: "memory");
    __builtin_amdgcn_sched_barrier(0);
    __builtin_amdgcn_s_barrier();
    cur ^= 1;
  }

  // epilogue: O/l -> bf16 [B,T,C] (attention output, input to final GEMM)
#pragma unroll
  for (int e = 0; e < 4; ++e) {
    float inv = 1.f / lrow[e];
    int qq = qw + g * 4 + e;
#pragma unroll
    for (int dt = 0; dt < 4; ++dt)
      o2[((size_t)(bi * 2048 + qq)) * 1024 + h * 64 + dt * 16 + r] = f2bf(accO[dt][e] * inv);
  }
}

extern "C" void kernel_launch(void* const* d_in, const int* in_sizes, int n_in,
                              void* d_out, int out_size, void* d_ws, size_t ws_size,
                              hipStream_t stream) {
  const float* x    = (const float*)d_in[0];
  const float* wqkv = (const float*)d_in[1];
  const float* wout = (const float*)d_in[2];
  const float* hsc  = (const float*)d_in[3];
  const float* hdir = (const float*)d_in[4];
  float* outp = (float*)d_out;

  char* ws = (char*)d_ws;
  unsigned short* xb    = (unsigned short*)(ws + 0);         //  8 MB  [4096][1024]
  unsigned short* wqkvT = (unsigned short*)(ws + 8388608);   //  6 MB  [3072][1024]
  unsigned short* woutT = (unsigned short*)(ws + 14680064);  //  2 MB  [1024][1024]
  unsigned short* qb    = (unsigned short*)(ws + 16777216);  //  8 MB  [32][2048][64]
  unsigned short* kb    = (unsigned short*)(ws + 25165824);  //  8 MB  [32][2048][64]
  unsigned short* vT    = (unsigned short*)(ws + 33554432);  //  8 MB  [32][64][2048]
  unsigned short* x2b   = (unsigned short*)(ws + 41943040);  //  8 MB  [4096][1024]
  if (ws_size < 50331648u) return;

  k_cast<<<4096, 256, 0, stream>>>(x, xb, 1048576);
  k_transpose<<<dim3(48, 16), 256, 0, stream>>>(wqkv, wqkvT, 1024, 3072);
  k_transpose<<<dim3(16, 16), 256, 0, stream>>>(wout, woutT, 1024, 1024);
  k_gemm<0><<<dim3(24, 32), 256, 0, stream>>>(xb, wqkvT, qb, kb, vT, nullptr);
  k_attn<<<dim3(1024), 256, 0, stream>>>(qb, kb, vT, hsc, hdir, x2b);
  k_gemm<1><<<dim3(8, 32), 256, 0, stream>>>(x2b, woutT, nullptr, nullptr, nullptr, outp);
}

// Round 3
// 132.187 us; speedup vs baseline: 1.5540x; 1.5094x over previous
//
#include <hip/hip_runtime.h>
#include <stdint.h>

// Problem: B=2, T=2048, C=1024, H=16, HD=64. M = B*T = 4096, 3C = 3072.
// Geo bias folded into Q:  q~[d] = q[d]*SCALE + hs*(q[:8]·dir)*dir[d] (d<8)
// log2(e) additionally folded into Q~ so softmax uses exp2 directly.

typedef float f32x4 __attribute__((ext_vector_type(4)));
typedef unsigned short u16x8 __attribute__((ext_vector_type(8)));
typedef unsigned short u16x4 __attribute__((ext_vector_type(4)));
typedef unsigned int u32x2 __attribute__((ext_vector_type(2)));
typedef __bf16 bf16x8 __attribute__((ext_vector_type(8)));

static __device__ __forceinline__ unsigned short f2bf(float f) {
  unsigned u = __float_as_uint(f);
  u += 0x7FFFu + ((u >> 16) & 1u);
  return (unsigned short)(u >> 16);
}
static __device__ __forceinline__ float bf2f(unsigned short s) {
  return __uint_as_float(((unsigned)s) << 16);
}
static __device__ __forceinline__ f32x4 mfma16(u16x8 a, u16x8 b, f32x4 c) {
  return __builtin_amdgcn_mfma_f32_16x16x32_bf16(
      __builtin_bit_cast(bf16x8, a), __builtin_bit_cast(bf16x8, b), c, 0, 0, 0);
}
static __device__ __forceinline__ unsigned cvtpk(float lo, float hi) {
  unsigned d;
  asm("v_cvt_pk_bf16_f32 %0, %1, %2" : "=v"(d) : "v"(lo), "v"(hi));
  return d;
}

#define GLD16(gp, lp) __builtin_amdgcn_global_load_lds( \
    (const __attribute__((address_space(1))) unsigned int*)(gp), \
    (__attribute__((address_space(3))) unsigned int*)(lp), 16, 0, 0)

// ---------------- cast x (fp32 -> bf16) ----------------
__global__ __launch_bounds__(256) void k_cast(const float* __restrict__ in,
                                              unsigned short* __restrict__ out, int n4) {
  int i = blockIdx.x * 256 + threadIdx.x;
  if (i >= n4) return;
  f32x4 v = *(const f32x4*)(in + (size_t)i * 4);
  u16x4 o;
#pragma unroll
  for (int j = 0; j < 4; ++j) o[j] = f2bf(v[j]);
  *(u16x4*)(out + (size_t)i * 4) = o;
}

// ---------------- transpose + cast: out[c][r] = bf16(in[r][c]) ----------------
__global__ __launch_bounds__(256) void k_transpose(const float* __restrict__ in,
                                                   unsigned short* __restrict__ out,
                                                   int R, int Cc) {
  __shared__ float t[64][65];
  int tr = blockIdx.y * 64, tc = blockIdx.x * 64;
  int tx = threadIdx.x & 15, ty = threadIdx.x >> 4;
#pragma unroll
  for (int i = 0; i < 4; ++i) {
    int rr = ty + i * 16;
    f32x4 v = *(const f32x4*)(in + (size_t)(tr + rr) * Cc + tc + tx * 4);
#pragma unroll
    for (int j = 0; j < 4; ++j) t[rr][tx * 4 + j] = v[j];
  }
  __syncthreads();
#pragma unroll
  for (int i = 0; i < 4; ++i) {
    int cc = ty + i * 16;
    int rr = tx * 4;
    u16x4 o;
#pragma unroll
    for (int j = 0; j < 4; ++j) o[j] = f2bf(t[rr + j][cc]);
    *(u16x4*)(out + (size_t)(tc + cc) * R + tr + rr) = o;
  }
}

// ---------------- GEMM: C[m][n] = sum_k A[m][k] * Bt[n][k]  (K=1024, 128x128 tile, BK=32)
template <int MODE>
__global__ __launch_bounds__(256) void k_gemm(const unsigned short* __restrict__ A,
                                              const unsigned short* __restrict__ Bt,
                                              unsigned short* __restrict__ qo,
                                              unsigned short* __restrict__ ko,
                                              unsigned short* __restrict__ vTo,
                                              float* __restrict__ fo) {
  __shared__ unsigned short lA[128 * 32];
  __shared__ unsigned short lB[128 * 32];
  const int tid = threadIdx.x;
  const int lane = tid & 63, wid = tid >> 6;
  const int wr = wid >> 1, wc = wid & 1;
  const int r = lane & 15, g = lane >> 4;
  const int mbase = blockIdx.y * 128;
  const int nbase = blockIdx.x * 128;

  f32x4 acc[4][4] = {};

  for (int kt = 0; kt < 32; ++kt) {
    __syncthreads();
#pragma unroll
    for (int p = 0; p < 2; ++p) {
      int L = p * 4096 + tid * 16;  // byte offset in 8KB tile
      int row = L >> 6;             // 64B per row (32 bf16)
      int blk = (L >> 4) & 3;       // 16B block within row
      GLD16(A + (size_t)(mbase + row) * 1024 + kt * 32 + blk * 8, lA + (L >> 1));
      GLD16(Bt + (size_t)(nbase + row) * 1024 + kt * 32 + blk * 8, lB + (L >> 1));
    }
    __syncthreads();
    u16x8 af[4], bfv[4];
#pragma unroll
    for (int m = 0; m < 4; ++m)
      af[m] = *(const u16x8*)(lA + (wr * 64 + m * 16 + r) * 32 + g * 8);
#pragma unroll
    for (int n = 0; n < 4; ++n)
      bfv[n] = *(const u16x8*)(lB + (wc * 64 + n * 16 + r) * 32 + g * 8);
#pragma unroll
    for (int m = 0; m < 4; ++m)
#pragma unroll
      for (int n = 0; n < 4; ++n) acc[m][n] = mfma16(af[m], bfv[n], acc[m][n]);
  }

#pragma unroll
  for (int m = 0; m < 4; ++m) {
#pragma unroll
    for (int n = 0; n < 4; ++n) {
      int ng = nbase + wc * 64 + n * 16 + r;
      int m0 = mbase + wr * 64 + m * 16 + g * 4;
      if (MODE == 0) {
        int sec = ng >> 10, rem = ng & 1023, hh = rem >> 6, d = rem & 63;
        int b = m0 >> 11, t0 = m0 & 2047;
        size_t bh = (size_t)(b * 16 + hh);
        if (sec == 2) {
          u16x4 o;
#pragma unroll
          for (int e = 0; e < 4; ++e) o[e] = f2bf(acc[m][n][e]);
          *(u16x4*)(vTo + (bh * 64 + d) * 2048 + t0) = o;  // V^T: [bh][d][t]
        } else {
          unsigned short* dst = (sec == 0 ? qo : ko);
#pragma unroll
          for (int e = 0; e < 4; ++e)
            dst[(bh * 2048 + t0 + e) * 64 + d] = f2bf(acc[m][n][e]);
        }
      } else {
#pragma unroll
        for (int e = 0; e < 4; ++e)
          fo[(size_t)(m0 + e) * 1024 + ng] = acc[m][n][e];
      }
    }
  }
}

// ---------------- causal flash attention, head_dim 64, folded E8 bias ----------------
// 512 blocks, each handles the q-tile PAIR (a, 31-a): exactly 33 K-iterations
// per block -> perfect balance. Swapped MFMAs (mfma(K,Q), mfma(V,P)) put each
// lane's q-row reductions in-register: softmax = 15-op tree + 2 shfl_xor.
// 3-deep LDS pipeline with counted vmcnt(4). XCD-aware bh decode.
__global__ __launch_bounds__(256) void k_attn(const unsigned short* __restrict__ qb,
                                              const unsigned short* __restrict__ kb,
                                              const unsigned short* __restrict__ vTb,
                                              const float* __restrict__ hsc,
                                              const float* __restrict__ hdir,
                                              unsigned short* __restrict__ o2) {
  __shared__ unsigned short lK[3][64 * 64];   // [buf][kpos][d], XOR-swizzled rows
  __shared__ unsigned short lV[3][64 * 64];   // [buf][d][kpos], XOR-swizzled rows
  __shared__ unsigned short lP[4][16 * 64];   // per-wave P bounce, swizzled

  const int tid = threadIdx.x, lane = tid & 63, wid = tid >> 6;
  const int r = lane & 15, g = lane >> 4;
  // XCD-locality decode: blocks sharing bh land on one XCD (bid%8 heuristic).
  const int bid = blockIdx.x;
  const int xcd = bid & 7, slot = bid >> 3;
  const int bh = xcd + 8 * (slot >> 4);   // 4 bh per XCD
  const int a = slot & 15;                // pair (a, 31-a)
  const int h = bh & 15, bi = bh >> 4;

  const size_t kbase = (size_t)bh * 2048 * 64;
  const size_t vbase = (size_t)bh * 64 * 2048;

  auto KT = [&](int i) { return (i <= a) ? i : i - (a + 1); };

  auto STAGE = [&](int buf, int kt) {
    unsigned short* dK = (unsigned short*)lK[buf];
    unsigned short* dV = (unsigned short*)lV[buf];
#pragma unroll
    for (int p = 0; p < 2; ++p) {
      int L = p * 4096 + tid * 16;
      int row = L >> 7;           // 128B rows (64 bf16)
      int cb = (L >> 4) & 7;
      int cbg = cb ^ (row & 7);   // pre-swizzled source -> swizzled reads, linear dest
      GLD16(kb + kbase + (size_t)(kt * 64 + row) * 64 + cbg * 8, dK + (L >> 1));
      GLD16(vTb + vbase + (size_t)row * 2048 + kt * 64 + cbg * 8, dV + (L >> 1));
    }
  };

  STAGE(0, 0);
  STAGE(1, KT(1));

  const float LOG2E = 1.44269504088896f;
  const float hs = hsc[h];
  float dir8[8];
#pragma unroll
  for (int j = 0; j < 8; ++j) dir8[j] = hdir[h * 8 + j];

  // Folded Q~ fragments for both tiles of the pair. Lane holds Q~[q=r][d-chunk g]
  // (B-operand of swapped QK^T). d<8 <=> (s==0 && g==0).
  auto QF = [&](int qt_, u16x8& d0, u16x8& d1) {
    const unsigned short* qrow = qb + ((size_t)bh * 2048 + qt_ * 64 + wid * 16 + r) * 64;
    float proj = 0.f;
    u16x8 qv = *(const u16x8*)qrow;
#pragma unroll
    for (int j = 0; j < 8; ++j) proj += bf2f(qv[j]) * dir8[j];
#pragma unroll
    for (int s = 0; s < 2; ++s) {
      u16x8 raw = *(const u16x8*)(qrow + s * 32 + g * 8);
      u16x8 ov;
#pragma unroll
      for (int j = 0; j < 8; ++j) {
        float v = bf2f(raw[j]) * (0.125f * LOG2E);
        if (s == 0 && g == 0) v += (hs * LOG2E) * proj * dir8[j];
        ov[j] = f2bf(v);
      }
      if (s == 0) d0 = ov; else d1 = ov;
    }
  };
  u16x8 qfA0, qfA1, qfB0, qfB1;
  QF(a, qfA0, qfA1);
  QF(31 - a, qfB0, qfB1);

  f32x4 accO[4] = {};
  float mrow = -1e30f, lrow = 0.f;
  u16x8 qc0 = qfA0, qc1 = qfA1;
  int qt = a, qw = a * 64 + wid * 16;
  int bcur = 0;

  unsigned short* pw = &lP[wid][0];

  for (int it = 0; it < 33; ++it) {
    const int kt = KT(it);

    // counted wait: tile-it's own 4 loads done (tile it+1's 4 may stay in flight)
    if (it < 32) {
      asm volatile("s_waitcnt vmcnt(4)" ::: "memory");
    } else {
      asm volatile("s_waitcnt vmcnt(0)" ::: "memory");
    }
    __builtin_amdgcn_sched_barrier(0);
    __builtin_amdgcn_s_barrier();   // all waves: tile-it landed, buf (it-1)%3 free
    __builtin_amdgcn_sched_barrier(0);

    if (it + 2 < 33) {
      int bn = bcur + 2; if (bn >= 3) bn -= 3;
      STAGE(bn, KT(it + 2));
    }

    const char* lKc = (const char*)lK[bcur];
    const char* lVc = (const char*)lV[bcur];

    // S = (K @ Q~^T)^T in log2 domain: lane holds S[q=r][k=ct*16+g*4+e]
    f32x4 accS[4];
    __builtin_amdgcn_s_setprio(1);
#pragma unroll
    for (int ct = 0; ct < 4; ++ct) {
      f32x4 s4 = {0.f, 0.f, 0.f, 0.f};
      {
        int krow = ct * 16 + r;
        int swz = (krow & 7) << 4;
        u16x8 kf0 = *(const u16x8*)(lKc + krow * 128 + ((g * 16) ^ swz));
        u16x8 kf1 = *(const u16x8*)(lKc + krow * 128 + ((64 + g * 16) ^ swz));
        s4 = mfma16(kf0, qc0, s4);
        s4 = mfma16(kf1, qc1, s4);
      }
      accS[ct] = s4;
    }
    __builtin_amdgcn_s_setprio(0);

    if (kt == qt) {  // diagonal tile: causal mask
#pragma unroll
      for (int ct = 0; ct < 4; ++ct)
#pragma unroll
        for (int e = 0; e < 4; ++e) {
          int kk = kt * 64 + ct * 16 + g * 4 + e;
          if (kk > qw + r) accS[ct][e] = -1e30f;
        }
    }

    // online softmax, per-lane q-row (q = r): in-register tree + 2 shuffles
    float mt[4];
#pragma unroll
    for (int ct = 0; ct < 4; ++ct)
      mt[ct] = fmaxf(fmaxf(accS[ct][0], accS[ct][1]), fmaxf(accS[ct][2], accS[ct][3]));
    float v = fmaxf(fmaxf(mt[0], mt[1]), fmaxf(mt[2], mt[3]));
    v = fmaxf(v, __shfl_xor(v, 16, 64));
    v = fmaxf(v, __shfl_xor(v, 32, 64));
    float mn = fmaxf(mrow, v);
    float alpha = exp2f(mrow - mn);
    mrow = mn;

    float p[4][4];
#pragma unroll
    for (int ct = 0; ct < 4; ++ct)
#pragma unroll
      for (int e = 0; e < 4; ++e) p[ct][e] = exp2f(accS[ct][e] - mn);

    float st[4];
#pragma unroll
    for (int ct = 0; ct < 4; ++ct)
      st[ct] = (p[ct][0] + p[ct][1]) + (p[ct][2] + p[ct][3]);
    float rs = (st[0] + st[1]) + (st[2] + st[3]);
    rs += __shfl_xor(rs, 16, 64);
    rs += __shfl_xor(rs, 32, 64);
    lrow = lrow * alpha + rs;

#pragma unroll
    for (int dt = 0; dt < 4; ++dt)
#pragma unroll
      for (int e = 0; e < 4; ++e) accO[dt][e] *= alpha;

    // P -> bf16 (cvt_pk) -> per-wave LDS bounce (b64 writes, XOR-swizzled)
    {
      int swz = (r & 7) << 4;
#pragma unroll
      for (int ct = 0; ct < 4; ++ct) {
        u32x2 w;
        w[0] = cvtpk(p[ct][0], p[ct][1]);
        w[1] = cvtpk(p[ct][2], p[ct][3]);
        *(u32x2*)((char*)pw + r * 128 + ((ct * 32 + g * 8) ^ swz)) = w;
      }
    }
    asm volatile("s_waitcnt lgkmcnt(0)" ::: "memory");
    __builtin_amdgcn_sched_barrier(0);

    // O^T += V^T @ P^T  (swapped): lane gets O[q=r][d=dt*16+g*4+e]
    __builtin_amdgcn_s_setprio(1);
#pragma unroll
    for (int s = 0; s < 2; ++s) {
      u16x8 pa = *(const u16x8*)((const char*)pw + r * 128 + ((s * 64 + g * 16) ^ ((r & 7) << 4)));
#pragma unroll
      for (int dt = 0; dt < 4; ++dt) {
        int dd = dt * 16 + r;
        u16x8 vf = *(const u16x8*)(lVc + dd * 128 + ((s * 64 + g * 16) ^ ((dd & 7) << 4)));
        accO[dt] = mfma16(vf, pa, accO[dt]);
      }
    }
    __builtin_amdgcn_s_setprio(0);

    if (it == qt || it == 32) {  // phase end (it==a for phase 0, it==32 for phase 1)
      float inv = 1.f / lrow;
      int qq = qw + r;
#pragma unroll
      for (int dt = 0; dt < 4; ++dt) {
        u16x4 o;
#pragma unroll
        for (int e = 0; e < 4; ++e) o[e] = f2bf(accO[dt][e] * inv);
        *(u16x4*)(o2 + ((size_t)(bi * 2048 + qq)) * 1024 + h * 64 + dt * 16 + g * 4) = o;
      }
      if (it == a) {  // reset for phase 1 (tile 31-a)
#pragma unroll
        for (int dt = 0; dt < 4; ++dt) accO[dt] = (f32x4){0.f, 0.f, 0.f, 0.f};
        mrow = -1e30f; lrow = 0.f;
        qt = 31 - a; qw = qt * 64 + wid * 16;
        qc0 = qfB0; qc1 = qfB1;
      }
    }

    asm volatile("s_waitcnt lgkmcnt(0)" ::: "memory");
    __builtin_amdgcn_sched_barrier(0);
    bcur = (bcur == 2) ? 0 : bcur + 1;
  }
}

extern "C" void kernel_launch(void* const* d_in, const int* in_sizes, int n_in,
                              void* d_out, int out_size, void* d_ws, size_t ws_size,
                              hipStream_t stream) {
  const float* x    = (const float*)d_in[0];
  const float* wqkv = (const float*)d_in[1];
  const float* wout = (const float*)d_in[2];
  const float* hsc  = (const float*)d_in[3];
  const float* hdir = (const float*)d_in[4];
  float* outp = (float*)d_out;

  char* ws = (char*)d_ws;
  unsigned short* xb    = (unsigned short*)(ws + 0);         //  8 MB  [4096][1024]
  unsigned short* wqkvT = (unsigned short*)(ws + 8388608);   //  6 MB  [3072][1024]
  unsigned short* woutT = (unsigned short*)(ws + 14680064);  //  2 MB  [1024][1024]
  unsigned short* qb    = (unsigned short*)(ws + 16777216);  //  8 MB  [32][2048][64]
  unsigned short* kb    = (unsigned short*)(ws + 25165824);  //  8 MB  [32][2048][64]
  unsigned short* vT    = (unsigned short*)(ws + 33554432);  //  8 MB  [32][64][2048]
  unsigned short* x2b   = (unsigned short*)(ws + 41943040);  //  8 MB  [4096][1024]
  if (ws_size < 50331648u) return;

  k_cast<<<4096, 256, 0, stream>>>(x, xb, 1048576);
  k_transpose<<<dim3(48, 16), 256, 0, stream>>>(wqkv, wqkvT, 1024, 3072);
  k_transpose<<<dim3(16, 16), 256, 0, stream>>>(wout, woutT, 1024, 1024);
  k_gemm<0><<<dim3(24, 32), 256, 0, stream>>>(xb, wqkvT, qb, kb, vT, nullptr);
  k_attn<<<dim3(512), 256, 0, stream>>>(qb, kb, vT, hsc, hdir, x2b);
  k_gemm<1><<<dim3(8, 32), 256, 0, stream>>>(x2b, woutT, nullptr, nullptr, nullptr, outp);
}